// Round 1
// baseline (747.584 us; speedup 1.0000x reference)
//
#include <hip/hip_runtime.h>

// Problem constants: B=4, C=128, N=64, HID=1536, PROJ=768
// x: [4,128,64,64,64] fp32 (512 MiB). out: [4,192,768] fp32.
// ws layout: feat [768][128] fp32 | h [768][1536] fp32 | part [4][768][768] fp32
//   total = 393216 + 4718592 + 9437184 = 14549 KB (~13.9 MB)

// ---------------- Stage 1: plane reductions of x^2 ----------------
// One block per (b,c) cube. 1024 threads, float4 loads.
// v = t + 1024*iter -> w4 = t&15 (fixed), h = t>>4 (fixed), d = iter.
__global__ __launch_bounds__(1024, 8)
void plane_reduce_kernel(const float* __restrict__ x, float* __restrict__ feat) {
    const int bc = blockIdx.x;            // b*128 + c
    const int b  = bc >> 7;
    const int c  = bc & 127;
    const float4* __restrict__ xp = (const float4*)x + (size_t)bc * 65536;
    const int t    = threadIdx.x;
    const int wv   = t >> 6;              // wave 0..15
    const int lane = t & 63;
    const int w4   = t & 15;              // float4 group in w
    const int h    = t >> 4;              // 0..63

    __shared__ float sumd_w[64][17];      // [d][wave], padded
    __shared__ float sumh_lds[64];
    __shared__ float sumw_lds[64];
    if (t < 64) { sumh_lds[t] = 0.f; sumw_lds[t] = 0.f; }
    __syncthreads();

    float sw0 = 0.f, sw1 = 0.f, sw2 = 0.f, sw3 = 0.f, sh = 0.f;

    float4 va = xp[t];
    float4 vb = xp[t + 1024];
    for (int d = 0; d < 64; d += 2) {
        const int dn = (d + 2) & 63;      // wraps at the end: redundant (harmless) reload
        float4 na = xp[t + (dn << 10)];
        float4 nb = xp[t + ((dn + 1) << 10)];
        {   // slice d
            float q0 = va.x * va.x, q1 = va.y * va.y, q2 = va.z * va.z, q3 = va.w * va.w;
            sw0 += q0; sw1 += q1; sw2 += q2; sw3 += q3;
            float s = (q0 + q1) + (q2 + q3);
            sh += s;
            #pragma unroll
            for (int off = 32; off; off >>= 1) s += __shfl_down(s, off, 64);
            if (lane == 0) sumd_w[d][wv] = s;
        }
        {   // slice d+1
            float q0 = vb.x * vb.x, q1 = vb.y * vb.y, q2 = vb.z * vb.z, q3 = vb.w * vb.w;
            sw0 += q0; sw1 += q1; sw2 += q2; sw3 += q3;
            float s = (q0 + q1) + (q2 + q3);
            sh += s;
            #pragma unroll
            for (int off = 32; off; off >>= 1) s += __shfl_down(s, off, 64);
            if (lane == 0) sumd_w[d + 1][wv] = s;
        }
        va = na; vb = nb;
    }

    atomicAdd(&sumh_lds[h], sh);
    atomicAdd(&sumw_lds[w4 * 4 + 0], sw0);
    atomicAdd(&sumw_lds[w4 * 4 + 1], sw1);
    atomicAdd(&sumw_lds[w4 * 4 + 2], sw2);
    atomicAdd(&sumw_lds[w4 * 4 + 3], sw3);
    __syncthreads();

    if (t < 64) {
        float sd = 0.f;
        #pragma unroll
        for (int i = 0; i < 16; ++i) sd += sumd_w[t][i];
        const float inv = 1.0f / 4096.0f;
        float* fb = feat + (size_t)b * 192 * 128 + c;
        fb[(size_t)t * 128]          = sd * inv;            // sc: row d
        fb[(size_t)(64 + t) * 128]   = sumh_lds[t] * inv;   // ss: row 64+h
        fb[(size_t)(128 + t) * 128]  = sumw_lds[t] * inv;   // sa: row 128+w
    }
}

// ---------------- GEMM1: h = relu(feat @ W1 + b1) ----------------
// M=768, K=128, N=1536. 64x64 tile, full K in LDS, 4x4 per thread.
__global__ __launch_bounds__(256, 2)
void gemm1_relu_kernel(const float* __restrict__ feat, const float* __restrict__ W1,
                       const float* __restrict__ b1, float* __restrict__ hbuf) {
    __shared__ float AsT[128][68];  // [k][m], padded (68*4 = 272 B, 16B-multiple)
    __shared__ float Bs[128][68];   // [k][n]
    const int t  = threadIdx.x;
    const int n0 = blockIdx.x * 64;
    const int m0 = blockIdx.y * 64;

    #pragma unroll
    for (int r = 0; r < 8; ++r) {       // A tile: 64 rows x 128 k
        int idx = t + 256 * r;          // 0..2047 float4s
        int row = idx >> 5;
        int kv  = idx & 31;
        float4 a = *(const float4*)(feat + (size_t)(m0 + row) * 128 + kv * 4);
        AsT[kv * 4 + 0][row] = a.x;
        AsT[kv * 4 + 1][row] = a.y;
        AsT[kv * 4 + 2][row] = a.z;
        AsT[kv * 4 + 3][row] = a.w;
    }
    #pragma unroll
    for (int r = 0; r < 8; ++r) {       // B tile: 128 k x 64 n
        int idx = t + 256 * r;
        int kr = idx >> 4;
        int nv = idx & 15;
        *(float4*)&Bs[kr][nv * 4] =
            *(const float4*)(W1 + (size_t)kr * 1536 + n0 + nv * 4);
    }
    __syncthreads();

    const int tm = t >> 4, tn = t & 15;
    float acc[4][4] = {};
    #pragma unroll 4
    for (int k = 0; k < 128; ++k) {
        float4 a  = *(const float4*)&AsT[k][tm * 4];
        float4 bv = *(const float4*)&Bs[k][tn * 4];
        float av[4] = {a.x, a.y, a.z, a.w};
        float bb[4] = {bv.x, bv.y, bv.z, bv.w};
        #pragma unroll
        for (int i = 0; i < 4; ++i)
            #pragma unroll
            for (int j = 0; j < 4; ++j)
                acc[i][j] += av[i] * bb[j];
    }

    float4 bias = *(const float4*)(b1 + n0 + tn * 4);
    float bb[4] = {bias.x, bias.y, bias.z, bias.w};
    #pragma unroll
    for (int i = 0; i < 4; ++i) {
        float4 o;
        o.x = fmaxf(acc[i][0] + bb[0], 0.f);
        o.y = fmaxf(acc[i][1] + bb[1], 0.f);
        o.z = fmaxf(acc[i][2] + bb[2], 0.f);
        o.w = fmaxf(acc[i][3] + bb[3], 0.f);
        *(float4*)(hbuf + (size_t)(m0 + tm * 4 + i) * 1536 + n0 + tn * 4) = o;
    }
}

// ---------------- GEMM2 (k-split partials): part[s] = h[:,ks] @ W2[ks,:] ----------------
// M=768, N=768, K=1536 split 4x384. 64x64 tile, 32-k LDS sub-chunks.
__global__ __launch_bounds__(256, 4)
void gemm2_partial_kernel(const float* __restrict__ hbuf, const float* __restrict__ W2,
                          float* __restrict__ part) {
    __shared__ float AsT[32][68];
    __shared__ float Bs[32][68];
    const int t  = threadIdx.x;
    const int n0 = blockIdx.x * 64;
    const int m0 = blockIdx.y * 64;
    const int k0 = blockIdx.z * 384;
    const int tm = t >> 4, tn = t & 15;
    float acc[4][4] = {};

    for (int kk = 0; kk < 384; kk += 32) {
        const int kb = k0 + kk;
        #pragma unroll
        for (int r = 0; r < 2; ++r) {   // A: 64 rows x 32 k
            int idx = t + 256 * r;      // 0..511 float4s
            int row = idx >> 3;
            int kv  = idx & 7;
            float4 a = *(const float4*)(hbuf + (size_t)(m0 + row) * 1536 + kb + kv * 4);
            AsT[kv * 4 + 0][row] = a.x;
            AsT[kv * 4 + 1][row] = a.y;
            AsT[kv * 4 + 2][row] = a.z;
            AsT[kv * 4 + 3][row] = a.w;
        }
        #pragma unroll
        for (int r = 0; r < 2; ++r) {   // B: 32 k x 64 n
            int idx = t + 256 * r;
            int kr = idx >> 4;
            int nv = idx & 15;
            *(float4*)&Bs[kr][nv * 4] =
                *(const float4*)(W2 + (size_t)(kb + kr) * 768 + n0 + nv * 4);
        }
        __syncthreads();
        #pragma unroll
        for (int k = 0; k < 32; ++k) {
            float4 a  = *(const float4*)&AsT[k][tm * 4];
            float4 bv = *(const float4*)&Bs[k][tn * 4];
            float av[4] = {a.x, a.y, a.z, a.w};
            float bb[4] = {bv.x, bv.y, bv.z, bv.w};
            #pragma unroll
            for (int i = 0; i < 4; ++i)
                #pragma unroll
                for (int j = 0; j < 4; ++j)
                    acc[i][j] += av[i] * bb[j];
        }
        __syncthreads();
    }

    float* po = part + (size_t)blockIdx.z * (768 * 768);
    #pragma unroll
    for (int i = 0; i < 4; ++i) {
        float4 o;
        o.x = acc[i][0]; o.y = acc[i][1]; o.z = acc[i][2]; o.w = acc[i][3];
        *(float4*)(po + (size_t)(m0 + tm * 4 + i) * 768 + n0 + tn * 4) = o;
    }
}

// ---------------- Reduce partials + bias ----------------
__global__ __launch_bounds__(256)
void reduce_bias_kernel(const float* __restrict__ part, const float* __restrict__ b2,
                        float* __restrict__ out) {
    const int idx = blockIdx.x * 256 + threadIdx.x;   // float4 index, 0..147455
    const float4* p = (const float4*)part;
    float4 s0 = p[idx];
    float4 s1 = p[idx + 147456];
    float4 s2 = p[idx + 2 * 147456];
    float4 s3 = p[idx + 3 * 147456];
    const int col4 = idx % 192;                       // 768/4 cols per row
    float4 bb = ((const float4*)b2)[col4];
    float4 o;
    o.x = s0.x + s1.x + s2.x + s3.x + bb.x;
    o.y = s0.y + s1.y + s2.y + s3.y + bb.y;
    o.z = s0.z + s1.z + s2.z + s3.z + bb.z;
    o.w = s0.w + s1.w + s2.w + s3.w + bb.w;
    ((float4*)out)[idx] = o;
}

extern "C" void kernel_launch(void* const* d_in, const int* in_sizes, int n_in,
                              void* d_out, int out_size, void* d_ws, size_t ws_size,
                              hipStream_t stream) {
    const float* x  = (const float*)d_in[0];
    const float* W1 = (const float*)d_in[1];
    const float* b1 = (const float*)d_in[2];
    const float* W2 = (const float*)d_in[3];
    const float* b2 = (const float*)d_in[4];
    float* out  = (float*)d_out;
    float* feat = (float*)d_ws;             // 768*128
    float* hbuf = feat + 768 * 128;         // 768*1536
    float* part = hbuf + 768 * 1536;        // 4*768*768

    hipLaunchKernelGGL(plane_reduce_kernel, dim3(512), dim3(1024), 0, stream, x, feat);
    hipLaunchKernelGGL(gemm1_relu_kernel, dim3(24, 12), dim3(256), 0, stream, feat, W1, b1, hbuf);
    hipLaunchKernelGGL(gemm2_partial_kernel, dim3(12, 12, 4), dim3(256), 0, stream, hbuf, W2, part);
    hipLaunchKernelGGL(reduce_bias_kernel, dim3(576), dim3(256), 0, stream, part, b2, out);
}